// Round 16
// baseline (77.150 us; speedup 1.0000x reference)
//
#include <hip/hip_runtime.h>
#include <hip/hip_bf16.h>

// ---------------- types / helpers ----------------
typedef __attribute__((ext_vector_type(8))) short short8_t;    // 8 x bf16 (4 VGPRs)
typedef __attribute__((ext_vector_type(4))) float f32x4_t;     // 16x16 MFMA acc
typedef __attribute__((ext_vector_type(16))) float f32x16_t;   // 32x32 MFMA acc
typedef __attribute__((ext_vector_type(2))) unsigned int uint2v_t;
typedef __attribute__((ext_vector_type(4))) unsigned int uint4v_t;

#define MFMA16(a, b, c) __builtin_amdgcn_mfma_f32_16x16x32_bf16((a), (b), (c), 0, 0, 0)
#define MFMA32(a, b, c) __builtin_amdgcn_mfma_f32_32x32x16_bf16((a), (b), (c), 0, 0, 0)

__device__ __forceinline__ unsigned short f2bf(float f) {
  unsigned int u = __float_as_uint(f);
  unsigned int r = (u + 0x7fffu + ((u >> 16) & 1u)) >> 16;
  return (unsigned short)r;
}
__device__ __forceinline__ float bf2f(unsigned short u) {
  return __uint_as_float(((unsigned int)u) << 16);
}

__device__ __forceinline__ unsigned int cvt_pk_bf16(float lo, float hi) {
  unsigned int r;
  asm("v_cvt_pk_bf16_f32 %0, %1, %2" : "=v"(r) : "v"(lo), "v"(hi));
  return r;
}

__device__ __forceinline__ float ex2(float x) {  // 2^x, single trans-pipe instr
  float r;
  asm("v_exp_f32 %0, %1" : "=v"(r) : "v"(x));
  return r;
}

// async DMA: 16B per lane, global -> LDS. LDS dest = uniform base + lane*16.
__device__ __forceinline__ void gload_lds16(const void* g, void* l) {
  __builtin_amdgcn_global_load_lds(
      (const __attribute__((address_space(1))) unsigned int*)g,
      (__attribute__((address_space(3))) unsigned int*)l, 16, 0, 0);
}

// ---------------- constants ----------------
#define NB 4
#define NC 128
#define NN 4096
#define NG 32
#define NS 6              // KV splits -> 768 blocks = 3/CU (VGPR law: 84 regs -> 3 waves/EU)
#define ATT_SCALE 0.08838834764831843f
#define QSCALE (0.08838834764831843f * 1.4426950408889634f)
#define FIXED_MAX2 14.426950408889634f   // 10 * log2(e)

// ---------------- K1: groupnorm stats + weight conversion (merged) ----------------
__global__ __launch_bounds__(256) void gn_stats_convw(const float* __restrict__ x,
                                                      const float* __restrict__ qkv_w,
                                                      const float* __restrict__ proj_w,
                                                      float* __restrict__ mean,
                                                      float* __restrict__ rstd,
                                                      unsigned short* __restrict__ wq,
                                                      unsigned short* __restrict__ wp) {
  if (blockIdx.x >= 128) {  // weight conversion blocks
    int i = (blockIdx.x - 128) * 256 + threadIdx.x;
    if (i < 384 * 128) wq[i] = f2bf(qkv_w[i]);
    if (i < 128 * 128) wp[i] = f2bf(proj_w[i]);
    return;
  }
  int bg = blockIdx.x;
  const float4* p = (const float4*)(x + (size_t)bg * 16384);
  float s = 0.f, ss = 0.f;
  for (int i = threadIdx.x; i < 4096; i += 256) {
    float4 v = p[i];
    s += v.x + v.y + v.z + v.w;
    ss += v.x * v.x + v.y * v.y + v.z * v.z + v.w * v.w;
  }
#pragma unroll
  for (int off = 32; off >= 1; off >>= 1) {
    s += __shfl_down(s, off);
    ss += __shfl_down(ss, off);
  }
  __shared__ float sb[4], ssb[4];
  int w = threadIdx.x >> 6;
  if ((threadIdx.x & 63) == 0) { sb[w] = s; ssb[w] = ss; }
  __syncthreads();
  if (threadIdx.x == 0) {
    float ts = sb[0] + sb[1] + sb[2] + sb[3];
    float tss = ssb[0] + ssb[1] + ssb[2] + ssb[3];
    float m = ts * (1.f / 16384.f);
    float var = tss * (1.f / 16384.f) - m * m;
    mean[bg] = m;
    rstd[bg] = rsqrtf(var + 1e-5f);
  }
}

// ---------------- K2: fused GN-apply + QKV GEMM, A from global (L2 broadcast) ----------
// Grid (256 nt, 4 b) = 1024 blocks = 4/CU. 16-n tiles. LDS: Bs 4KB + T 5KB.
// A-fragments (weights) read directly from global: 16B/lane, identical across blocks.
__global__ __launch_bounds__(256) void qkv_gemm(const float* __restrict__ x,
                                                const float* __restrict__ mean,
                                                const float* __restrict__ rstd,
                                                const float* __restrict__ gw,
                                                const float* __restrict__ gb,
                                                const unsigned short* __restrict__ wq,
                                                const float* __restrict__ bias,
                                                unsigned short* __restrict__ q_t,
                                                unsigned short* __restrict__ k_t,
                                                unsigned short* __restrict__ v) {
  __shared__ __align__(16) char Bs[16 * 256];           // 16 n-rows, swizzled
  __shared__ __align__(16) unsigned short T[128 * 20];  // GN'd x, [c][16n + 4 pad]
  int nt = blockIdx.x, b = blockIdx.y;
  int tid = threadIdx.x, l = tid & 63;
  int n0 = nt * 16;

  // phase 1: x -> GN -> bf16 -> T[c][n]  (2 threads per channel, 8 n each)
  {
    int c = tid >> 1, half = tid & 1;
    int g = c >> 2;
    float m = mean[b * NG + g], rs = rstd[b * NG + g];
    float sc = gw[c] * rs, off = gb[c] - m * sc;
    const float4* xr = (const float4*)(x + (size_t)b * NC * NN + (size_t)c * NN + n0 + half * 8);
    unsigned short* tr = T + c * 20 + half * 8;
#pragma unroll
    for (int j = 0; j < 2; ++j) {
      float4 vv = xr[j];
      unsigned int p0 = (unsigned int)f2bf(vv.x * sc + off) |
                        ((unsigned int)f2bf(vv.y * sc + off) << 16);
      unsigned int p1 = (unsigned int)f2bf(vv.z * sc + off) |
                        ((unsigned int)f2bf(vv.w * sc + off) << 16);
      *(unsigned int*)(tr + j * 4) = p0;
      *(unsigned int*)(tr + j * 4 + 2) = p1;
    }
  }
  __syncthreads();

  // phase 2: T -> Bs (transpose + swizzle); 256 16B-units, 1 per thread
  {
    int n = tid >> 4, slot = tid & 15;
    int c0 = slot * 8;
    uint4 packed;
    packed.x = (unsigned int)T[(c0 + 0) * 20 + n] | ((unsigned int)T[(c0 + 1) * 20 + n] << 16);
    packed.y = (unsigned int)T[(c0 + 2) * 20 + n] | ((unsigned int)T[(c0 + 3) * 20 + n] << 16);
    packed.z = (unsigned int)T[(c0 + 4) * 20 + n] | ((unsigned int)T[(c0 + 5) * 20 + n] << 16);
    packed.w = (unsigned int)T[(c0 + 6) * 20 + n] | ((unsigned int)T[(c0 + 7) * 20 + n] << 16);
    *(uint4*)(Bs + n * 256 + ((slot << 4) ^ ((n & 7) << 4))) = packed;
  }
  __syncthreads();

  int w = tid >> 6;
  int arow_l = l & 15;
  int kq = l >> 4;
  int rbase = kq * 4;
  int cl = l & 15;

#pragma unroll
  for (int dt = 0; dt < 3; ++dt) {
    f32x4_t acc[2] = {};
#pragma unroll
    for (int kk = 0; kk < 4; ++kk) {
      short8_t aF[2], bF;
#pragma unroll
      for (int mi = 0; mi < 2; ++mi) {
        int r = dt * 128 + w * 32 + mi * 16 + arow_l;
        aF[mi] = *(const short8_t*)(wq + (size_t)r * NC + kk * 32 + kq * 8);
      }
      int rr = arow_l;
      bF = *(const short8_t*)(Bs + rr * 256 + ((kk * 64 + kq * 16) ^ ((rr & 7) << 4)));
#pragma unroll
      for (int mi = 0; mi < 2; ++mi)
        acc[mi] = MFMA16(aF[mi], bF, acc[mi]);
    }

#pragma unroll
    for (int mi = 0; mi < 2; ++mi) {
      int n = n0 + cl;
#pragma unroll
      for (int r = 0; r < 4; ++r) {
        int d = dt * 128 + w * 32 + mi * 16 + rbase + r;
        float val = acc[mi][r] + bias[d];
        if (dt == 0)
          q_t[((size_t)b * NN + n) * NC + d] = f2bf(val * QSCALE);
        else if (dt == 1)
          k_t[((size_t)b * NN + n) * NC + (d - 128)] = f2bf(val);
        else
          v[((size_t)b * NC + (d - 256)) * NN + n] = f2bf(val);
      }
    }
  }
}

// ---------------- K4: fused combine + proj + residual, A from global ----------------
// Grid (256 nt, 4 b) = 1024 blocks = 4/CU. 16-n tiles. LDS: Bs 4KB + invl.
__global__ __launch_bounds__(256) void proj_gemm(const unsigned short* __restrict__ wp,
                                                 const unsigned short* __restrict__ O_p,
                                                 const float* __restrict__ lp,
                                                 const float* __restrict__ bias,
                                                 const float* __restrict__ xres,
                                                 float* __restrict__ out) {
  __shared__ __align__(16) char Bs[16 * 256];
  __shared__ float invl[16];
  int nt = blockIdx.x, b = blockIdx.y;
  int tid = threadIdx.x, l = tid & 63;
  int n0 = nt * 16;

  if (tid < 16) {
    float ls = 0.f;
#pragma unroll
    for (int s2 = 0; s2 < NS; ++s2)
      ls += lp[(size_t)(b * NS + s2) * NN + n0 + tid];
    invl[tid] = 1.f / ls;
  }
  // stage B = sum of NS bf16 O-partials, swizzled (16 rows x 16 slots, 1 unit/thread)
  {
    int row = tid >> 4, sl = tid & 15;
    float f[8] = {};
#pragma unroll
    for (int s2 = 0; s2 < NS; ++s2) {
      const unsigned short* p =
          O_p + ((size_t)(b * NS + s2) * NN + n0 + row) * 128 + sl * 8;
      ushort4 u0 = *(const ushort4*)p;
      ushort4 u1 = *(const ushort4*)(p + 4);
      f[0] += bf2f(u0.x); f[1] += bf2f(u0.y); f[2] += bf2f(u0.z); f[3] += bf2f(u0.w);
      f[4] += bf2f(u1.x); f[5] += bf2f(u1.y); f[6] += bf2f(u1.z); f[7] += bf2f(u1.w);
    }
    uint4 packed;
    packed.x = (unsigned int)f2bf(f[0]) | ((unsigned int)f2bf(f[1]) << 16);
    packed.y = (unsigned int)f2bf(f[2]) | ((unsigned int)f2bf(f[3]) << 16);
    packed.z = (unsigned int)f2bf(f[4]) | ((unsigned int)f2bf(f[5]) << 16);
    packed.w = (unsigned int)f2bf(f[6]) | ((unsigned int)f2bf(f[7]) << 16);
    *(uint4*)(Bs + row * 256 + ((sl << 4) ^ ((row & 7) << 4))) = packed;
  }
  __syncthreads();

  int w = tid >> 6;
  int arow_l = l & 15;
  int kq = l >> 4;
  f32x4_t acc[2] = {};
#pragma unroll
  for (int kk = 0; kk < 4; ++kk) {
    short8_t aF[2], bF;
#pragma unroll
    for (int mi = 0; mi < 2; ++mi) {
      int r = w * 32 + mi * 16 + arow_l;
      aF[mi] = *(const short8_t*)(wp + (size_t)r * NC + kk * 32 + kq * 8);
    }
    int rr = arow_l;
    bF = *(const short8_t*)(Bs + rr * 256 + ((kk * 64 + kq * 16) ^ ((rr & 7) << 4)));
#pragma unroll
    for (int mi = 0; mi < 2; ++mi)
      acc[mi] = MFMA16(aF[mi], bF, acc[mi]);
  }

  int rbase = kq * 4;
  int cl = l & 15;
  float invl_c = invl[cl];
#pragma unroll
  for (int mi = 0; mi < 2; ++mi) {
    int n = n0 + cl;
#pragma unroll
    for (int r = 0; r < 4; ++r) {
      int d = w * 32 + mi * 16 + rbase + r;
      float val = acc[mi][r] * invl_c + bias[d];
      size_t idx = ((size_t)b * NC + d) * NN + n;
      out[idx] = xres[idx] + val;
    }
  }
}

// ---------------- K3: flash attention (byte-identical to rounds 13-15) ----------------
__device__ __forceinline__ void issue_kv32(const char* __restrict__ gKt,
                                           const char* __restrict__ gVt,
                                           char* Kbuf, char* Vbuf, int wg, int lane) {
#pragma unroll
  for (int i = 0; i < 2; ++i) {
    int ci = wg * 2 + i;
    int row = ci * 4 + (lane >> 4);                 // kv pos 0..31
    int col = (lane & 15) << 4;                     // 0..255
    gload_lds16(gKt + row * 256 + (col ^ ((row & 7) << 4)), Kbuf + ci * 1024);
  }
#pragma unroll
  for (int i = 0; i < 2; ++i) {
    int ci = wg * 2 + i;
    int rowl = lane >> 3;                           // row within chunk 0..7
    int sl = (lane & 7) ^ rowl;                     // logical slot (involution)
    int c = (ci * 8 + rowl) * 2 + (sl >> 2);        // channel 0..127
    int k16 = sl & 3;                               // 16B chunk within 64B kv window
    gload_lds16(gVt + (size_t)c * (NN * 2) + k16 * 16, Vbuf + ci * 1024);
  }
}

__global__ __launch_bounds__(256, 3) void attn(const unsigned short* __restrict__ q_t,
                                               const unsigned short* __restrict__ k_t,
                                               const unsigned short* __restrict__ v,
                                               unsigned short* __restrict__ O_p,
                                               float* __restrict__ l_p) {
  __shared__ __align__(16) char lds[32768];  // K0,K1 at 0,8K | V0,V1 at 16K,24K
  int qt = blockIdx.x, s = blockIdx.y, b = blockIdx.z;
  int tid = threadIdx.x, l = tid & 63, wg = tid >> 6;
  int ql = l & 31, qh = l >> 5;

  int t0 = 21 * s + min(s, 2);
  int cnt = 21 + (s < 2 ? 1 : 0);

  const char* gK = (const char*)(k_t + (size_t)b * NN * NC);
  const char* gV = (const char*)(v + (size_t)b * NC * NN);

  const unsigned short* gQ = q_t + ((size_t)b * NN + qt * 128 + wg * 32) * NC;
  short8_t bQ[8];
#pragma unroll
  for (int kk = 0; kk < 8; ++kk)
    bQ[kk] = *(const short8_t*)(gQ + (size_t)ql * NC + kk * 16 + qh * 8);

  issue_kv32(gK + (size_t)t0 * 8192, gV + (size_t)t0 * 64, lds, lds + 16384, wg, l);
  __syncthreads();

  f32x16_t oacc[4] = {};
  float lsum0 = 0.f, lsum1 = 0.f;

  for (int ti = 0; ti < cnt; ++ti) {
    int co = (ti & 1) << 13;
    int no = co ^ 8192;
    if (ti + 1 < cnt)
      issue_kv32(gK + (size_t)(t0 + ti + 1) * 8192, gV + (size_t)(t0 + ti + 1) * 64,
                 lds + no, lds + 16384 + no, wg, l);
    const char* Ks = lds + co;
    const char* Vs = lds + 16384 + co;

    f32x16_t sacc = {};
    __builtin_amdgcn_s_setprio(1);
#pragma unroll
    for (int kk = 0; kk < 8; ++kk) {
      short8_t aK = *(const short8_t*)(Ks + ql * 256 + ((kk * 32 + qh * 16) ^ ((ql & 7) << 4)));
      sacc = MFMA32(aK, bQ[kk], sacc);
    }
    __builtin_amdgcn_s_setprio(0);

    float p[16];
#pragma unroll
    for (int r = 0; r < 16; ++r) {
      p[r] = ex2(sacc[r] - FIXED_MAX2);
      if (r & 8) lsum1 += p[r]; else lsum0 += p[r];
    }

    unsigned int A0 = cvt_pk_bf16(p[0], p[1]), A1 = cvt_pk_bf16(p[2], p[3]);
    unsigned int B0 = cvt_pk_bf16(p[4], p[5]), B1 = cvt_pk_bf16(p[6], p[7]);
    unsigned int C0 = cvt_pk_bf16(p[8], p[9]), C1 = cvt_pk_bf16(p[10], p[11]);
    unsigned int D0 = cvt_pk_bf16(p[12], p[13]), D1 = cvt_pk_bf16(p[14], p[15]);
    uint2v_t r0 = __builtin_amdgcn_permlane32_swap(A0, B0, false, false);
    uint2v_t r1 = __builtin_amdgcn_permlane32_swap(A1, B1, false, false);
    uint2v_t r2 = __builtin_amdgcn_permlane32_swap(C0, D0, false, false);
    uint2v_t r3 = __builtin_amdgcn_permlane32_swap(C1, D1, false, false);
    uint4v_t pa0 = {r0.x, r1.x, r0.y, r1.y};   // kv (qh*8 + 0..7)
    uint4v_t pa1 = {r2.x, r3.x, r2.y, r3.y};   // kv (16 + qh*8 + 0..7)
    short8_t PA0 = __builtin_bit_cast(short8_t, pa0);
    short8_t PA1 = __builtin_bit_cast(short8_t, pa1);

    __builtin_amdgcn_s_setprio(1);
#pragma unroll
    for (int cb = 0; cb < 4; ++cb) {
#pragma unroll
      for (int ks = 0; ks < 2; ++ks) {
        int c = cb * 32 + ql;
        int row = c >> 1;
        int sl = ((c & 1) << 2) | (ks << 1) | qh;
        int pp = sl ^ (row & 7);
        short8_t aV = *(const short8_t*)(Vs + row * 128 + pp * 16);
        oacc[cb] = MFMA32(ks ? PA1 : PA0, aV, oacc[cb]);
      }
    }
    __builtin_amdgcn_s_setprio(0);

    __syncthreads();
  }

  float lanesum = lsum0 + lsum1;
  lanesum += __shfl_xor(lanesum, 32);

  unsigned short* Ob = O_p + ((size_t)(b * NS + s) * NN + qt * 128 + wg * 32) * 128;
#pragma unroll
  for (int r = 0; r < 16; ++r) {
    int q = (r & 3) + 8 * (r >> 2) + 4 * qh;
#pragma unroll
    for (int cb = 0; cb < 4; ++cb)
      Ob[(size_t)q * 128 + cb * 32 + ql] = f2bf(oacc[cb][r]);
  }
  if (l < 32)
    l_p[(size_t)(b * NS + s) * NN + qt * 128 + wg * 32 + ql] = lanesum;
}

// ---------------- launch ----------------
extern "C" void kernel_launch(void* const* d_in, const int* in_sizes, int n_in,
                              void* d_out, int out_size, void* d_ws, size_t ws_size,
                              hipStream_t stream) {
  const float* x = (const float*)d_in[0];
  const float* norm_w = (const float*)d_in[1];
  const float* norm_b = (const float*)d_in[2];
  const float* qkv_w = (const float*)d_in[3];
  const float* qkv_b = (const float*)d_in[4];
  const float* proj_w = (const float*)d_in[5];
  const float* proj_b = (const float*)d_in[6];
  float* out = (float*)d_out;

  char* ws = (char*)d_ws;
  float* mean = (float*)ws;
  float* rstd = (float*)(ws + 512);
  unsigned short* wq = (unsigned short*)(ws + 4096);
  unsigned short* wp = (unsigned short*)(ws + 4096 + 98304);
  const size_t TEN = (size_t)NB * NN * NC;          // 2M elems, 4MB bf16
  unsigned short* q_t = (unsigned short*)(ws + (1 << 18));
  unsigned short* k_t = q_t + TEN;
  unsigned short* v = k_t + TEN;
  unsigned short* O_p = (unsigned short*)(ws + (1 << 18) + 3 * TEN * 2);  // NS*4MB bf16
  float* l_p = (float*)((char*)O_p + (size_t)NS * NB * NN * NC * 2);      // NS*4*4096 f32

  gn_stats_convw<<<320, 256, 0, stream>>>(x, qkv_w, proj_w, mean, rstd, wq, wp);
  qkv_gemm<<<dim3(NN / 16, NB), 256, 0, stream>>>(x, mean, rstd, norm_w, norm_b,
                                                  wq, qkv_b, q_t, k_t, v);
  attn<<<dim3(NN / 128, NS, NB), 256, 0, stream>>>(q_t, k_t, v, O_p, l_p);
  proj_gemm<<<dim3(NN / 16, NB), 256, 0, stream>>>(wp, O_p, l_p, proj_b, x, out);
}

// Round 17
// 69.319 us; speedup vs baseline: 1.1130x; 1.1130x over previous
//
#include <hip/hip_runtime.h>
#include <hip/hip_bf16.h>

// ---------------- types / helpers ----------------
typedef __attribute__((ext_vector_type(8))) short short8_t;    // 8 x bf16 (4 VGPRs)
typedef __attribute__((ext_vector_type(4))) float f32x4_t;     // 16x16 MFMA acc
typedef __attribute__((ext_vector_type(16))) float f32x16_t;   // 32x32 MFMA acc
typedef __attribute__((ext_vector_type(2))) unsigned int uint2v_t;
typedef __attribute__((ext_vector_type(4))) unsigned int uint4v_t;

#define MFMA16(a, b, c) __builtin_amdgcn_mfma_f32_16x16x32_bf16((a), (b), (c), 0, 0, 0)
#define MFMA32(a, b, c) __builtin_amdgcn_mfma_f32_32x32x16_bf16((a), (b), (c), 0, 0, 0)

__device__ __forceinline__ unsigned short f2bf(float f) {
  unsigned int u = __float_as_uint(f);
  unsigned int r = (u + 0x7fffu + ((u >> 16) & 1u)) >> 16;
  return (unsigned short)r;
}
__device__ __forceinline__ float bf2f(unsigned short u) {
  return __uint_as_float(((unsigned int)u) << 16);
}

__device__ __forceinline__ unsigned int cvt_pk_bf16(float lo, float hi) {
  unsigned int r;
  asm("v_cvt_pk_bf16_f32 %0, %1, %2" : "=v"(r) : "v"(lo), "v"(hi));
  return r;
}

__device__ __forceinline__ float ex2(float x) {  // 2^x, single trans-pipe instr
  float r;
  asm("v_exp_f32 %0, %1" : "=v"(r) : "v"(x));
  return r;
}

// async DMA: 16B per lane, global -> LDS. LDS dest = uniform base + lane*16.
__device__ __forceinline__ void gload_lds16(const void* g, void* l) {
  __builtin_amdgcn_global_load_lds(
      (const __attribute__((address_space(1))) unsigned int*)g,
      (__attribute__((address_space(3))) unsigned int*)l, 16, 0, 0);
}

// Async-stage a [nrows][256B] tile (contiguous rows) into LDS with the XOR swizzle
// applied via pre-swizzled SOURCE (involution; LDS dest linear). 1KB per chunk.
__device__ __forceinline__ void stage_gload_256(const char* __restrict__ g,
                                                char* lds, int nchunks,
                                                int wg, int nw, int lane) {
  for (int c = wg; c < nchunks; c += nw) {
    int row = c * 4 + (lane >> 4);
    int srco = row * 256 + ((((lane & 15) << 4)) ^ ((row & 7) << 4));
    gload_lds16(g + srco, lds + c * 1024);
  }
}

// ---------------- constants ----------------
#define NB 4
#define NC 128
#define NN 4096
#define NG 32
#define NS 6              // KV splits -> 768 blocks = 3/CU (VGPR law: 84 regs -> 3 waves/EU)
#define ATT_SCALE 0.08838834764831843f
#define QSCALE (0.08838834764831843f * 1.4426950408889634f)
#define FIXED_MAX2 14.426950408889634f   // 10 * log2(e)

// ---------------- K1: groupnorm stats + weight conversion (merged) ----------------
__global__ __launch_bounds__(256) void gn_stats_convw(const float* __restrict__ x,
                                                      const float* __restrict__ qkv_w,
                                                      const float* __restrict__ proj_w,
                                                      float* __restrict__ mean,
                                                      float* __restrict__ rstd,
                                                      unsigned short* __restrict__ wq,
                                                      unsigned short* __restrict__ wp) {
  if (blockIdx.x >= 128) {  // weight conversion blocks
    int i = (blockIdx.x - 128) * 256 + threadIdx.x;
    if (i < 384 * 128) wq[i] = f2bf(qkv_w[i]);
    if (i < 128 * 128) wp[i] = f2bf(proj_w[i]);
    return;
  }
  int bg = blockIdx.x;
  const float4* p = (const float4*)(x + (size_t)bg * 16384);
  float s = 0.f, ss = 0.f;
  for (int i = threadIdx.x; i < 4096; i += 256) {
    float4 v = p[i];
    s += v.x + v.y + v.z + v.w;
    ss += v.x * v.x + v.y * v.y + v.z * v.z + v.w * v.w;
  }
#pragma unroll
  for (int off = 32; off >= 1; off >>= 1) {
    s += __shfl_down(s, off);
    ss += __shfl_down(ss, off);
  }
  __shared__ float sb[4], ssb[4];
  int w = threadIdx.x >> 6;
  if ((threadIdx.x & 63) == 0) { sb[w] = s; ssb[w] = ss; }
  __syncthreads();
  if (threadIdx.x == 0) {
    float ts = sb[0] + sb[1] + sb[2] + sb[3];
    float tss = ssb[0] + ssb[1] + ssb[2] + ssb[3];
    float m = ts * (1.f / 16384.f);
    float var = tss * (1.f / 16384.f) - m * m;
    mean[bg] = m;
    rstd[bg] = rsqrtf(var + 1e-5f);
  }
}

// ---------------- K2: fused GN-apply + QKV GEMM, dt merged (round-15 winner) ----------
// Grid (64 nt, 4 b) = 256 blocks. Per block: DMA all 384 weight rows (96KB) -> As;
// GN its 64-n x-slice ONCE -> T -> Bs; one barrier; barrier-free dt-loop.
__global__ __launch_bounds__(256) void qkv_gemm(const float* __restrict__ x,
                                                const float* __restrict__ mean,
                                                const float* __restrict__ rstd,
                                                const float* __restrict__ gw,
                                                const float* __restrict__ gb,
                                                const unsigned short* __restrict__ wq,
                                                const float* __restrict__ bias,
                                                unsigned short* __restrict__ q_t,
                                                unsigned short* __restrict__ k_t,
                                                unsigned short* __restrict__ v) {
  __shared__ __align__(16) char As[384 * 256];          // all 3 dt weight tiles, swizzled
  __shared__ __align__(16) char Bs[64 * 256];           // 64 n-rows, swizzled
  __shared__ __align__(16) unsigned short T[128 * 72];  // GN'd x, [c][n(+pad)]
  int nt = blockIdx.x, b = blockIdx.y;
  int tid = threadIdx.x, l = tid & 63, wgv = tid >> 6;
  int n0 = nt * 64;

  // async staging of all 384 weight rows (96 chunks of 1KB)
  stage_gload_256((const char*)wq, As, 96, wgv, 4, l);

  // phase 1: x -> GN -> bf16 -> T[c][n]   (done ONCE, not per dt)
  {
    int c = tid >> 1, half = tid & 1;
    int g = c >> 2;
    float m = mean[b * NG + g], rs = rstd[b * NG + g];
    float sc = gw[c] * rs, off = gb[c] - m * sc;
    const float4* xr = (const float4*)(x + (size_t)b * NC * NN + (size_t)c * NN + n0 + half * 32);
    unsigned short* tr = T + c * 72 + half * 32;
#pragma unroll
    for (int j = 0; j < 8; ++j) {
      float4 vv = xr[j];
      unsigned int p0 = (unsigned int)f2bf(vv.x * sc + off) |
                        ((unsigned int)f2bf(vv.y * sc + off) << 16);
      unsigned int p1 = (unsigned int)f2bf(vv.z * sc + off) |
                        ((unsigned int)f2bf(vv.w * sc + off) << 16);
      *(unsigned int*)(tr + j * 4) = p0;
      *(unsigned int*)(tr + j * 4 + 2) = p1;
    }
  }
  __syncthreads();

  // phase 2: T -> Bs (transpose + swizzle); 1024 16B-units
  for (int u = tid; u < 1024; u += 256) {
    int n = u >> 4, slot = u & 15;
    int c0 = slot * 8;
    uint4 packed;
    packed.x = (unsigned int)T[(c0 + 0) * 72 + n] | ((unsigned int)T[(c0 + 1) * 72 + n] << 16);
    packed.y = (unsigned int)T[(c0 + 2) * 72 + n] | ((unsigned int)T[(c0 + 3) * 72 + n] << 16);
    packed.z = (unsigned int)T[(c0 + 4) * 72 + n] | ((unsigned int)T[(c0 + 5) * 72 + n] << 16);
    packed.w = (unsigned int)T[(c0 + 6) * 72 + n] | ((unsigned int)T[(c0 + 7) * 72 + n] << 16);
    *(uint4*)(Bs + n * 256 + ((slot << 4) ^ ((n & 7) << 4))) = packed;
  }
  __syncthreads();  // drains all A DMA (vmcnt) + Bs writes; no more barriers below

  int w = tid >> 6;
  int arow0 = w * 32 + (l & 15);
  int brow0 = (l & 15);
  int kbyte0 = (l >> 4) * 16;
  int rbase = (l >> 4) * 4;
  int cl = l & 15;

#pragma unroll
  for (int dt = 0; dt < 3; ++dt) {
    const char* Ad = As + dt * 32768;
    f32x4_t acc[2][4] = {};
#pragma unroll
    for (int kk = 0; kk < 4; ++kk) {
      int kb = kk * 64 + kbyte0;
      short8_t aF[2], bF[4];
#pragma unroll
      for (int mi = 0; mi < 2; ++mi) {
        int r = arow0 + mi * 16;
        aF[mi] = *(const short8_t*)(Ad + r * 256 + (kb ^ ((r & 7) << 4)));
      }
#pragma unroll
      for (int ni = 0; ni < 4; ++ni) {
        int r = brow0 + ni * 16;
        bF[ni] = *(const short8_t*)(Bs + r * 256 + (kb ^ ((r & 7) << 4)));
      }
#pragma unroll
      for (int mi = 0; mi < 2; ++mi)
#pragma unroll
        for (int ni = 0; ni < 4; ++ni)
          acc[mi][ni] = MFMA16(aF[mi], bF[ni], acc[mi][ni]);
    }

#pragma unroll
    for (int mi = 0; mi < 2; ++mi) {
#pragma unroll
      for (int ni = 0; ni < 4; ++ni) {
        int n = n0 + ni * 16 + cl;
#pragma unroll
        for (int r = 0; r < 4; ++r) {
          int d = dt * 128 + w * 32 + mi * 16 + rbase + r;
          float val = acc[mi][ni][r] + bias[d];
          if (dt == 0)
            q_t[((size_t)b * NN + n) * NC + d] = f2bf(val * QSCALE);
          else if (dt == 1)
            k_t[((size_t)b * NN + n) * NC + (d - 128)] = f2bf(val);
          else
            v[((size_t)b * NC + (d - 256)) * NN + n] = f2bf(val);
        }
      }
    }
  }
}

// ---------------- K4: fused combine + proj + residual, 32-n tiles (round-15) --------
// Grid (128 nt, 1, 4) = 512 blocks = 2/CU.
__global__ __launch_bounds__(256) void proj_gemm(const unsigned short* __restrict__ wp,
                                                 const unsigned short* __restrict__ O_p,
                                                 const float* __restrict__ lp,
                                                 const float* __restrict__ bias,
                                                 const float* __restrict__ xres,
                                                 float* __restrict__ out) {
  __shared__ __align__(16) char As[128 * 256];
  __shared__ __align__(16) char Bs[32 * 256];
  __shared__ float invl[32];
  int nt = blockIdx.x, b = blockIdx.z;
  int tid = threadIdx.x, l = tid & 63, wgv = tid >> 6;
  int n0 = nt * 32;

  stage_gload_256((const char*)wp, As, 32, wgv, 4, l);

  if (tid < 32) {
    float ls = 0.f;
#pragma unroll
    for (int s2 = 0; s2 < NS; ++s2)
      ls += lp[(size_t)(b * NS + s2) * NN + n0 + tid];
    invl[tid] = 1.f / ls;
  }
  // stage B = sum of NS bf16 O-partials, swizzled (32 rows x 16 slots)
  for (int i = tid; i < 32 * 16; i += 256) {
    int row = i >> 4, sl = i & 15;
    float f[8] = {};
#pragma unroll
    for (int s2 = 0; s2 < NS; ++s2) {
      const unsigned short* p =
          O_p + ((size_t)(b * NS + s2) * NN + n0 + row) * 128 + sl * 8;
      ushort4 u0 = *(const ushort4*)p;
      ushort4 u1 = *(const ushort4*)(p + 4);
      f[0] += bf2f(u0.x); f[1] += bf2f(u0.y); f[2] += bf2f(u0.z); f[3] += bf2f(u0.w);
      f[4] += bf2f(u1.x); f[5] += bf2f(u1.y); f[6] += bf2f(u1.z); f[7] += bf2f(u1.w);
    }
    uint4 packed;
    packed.x = (unsigned int)f2bf(f[0]) | ((unsigned int)f2bf(f[1]) << 16);
    packed.y = (unsigned int)f2bf(f[2]) | ((unsigned int)f2bf(f[3]) << 16);
    packed.z = (unsigned int)f2bf(f[4]) | ((unsigned int)f2bf(f[5]) << 16);
    packed.w = (unsigned int)f2bf(f[6]) | ((unsigned int)f2bf(f[7]) << 16);
    *(uint4*)(Bs + row * 256 + ((sl << 4) ^ ((row & 7) << 4))) = packed;
  }
  __syncthreads();

  int w = tid >> 6;
  f32x4_t acc[2][2] = {};
  int arow0 = w * 32 + (l & 15);
  int brow0 = (l & 15);
  int kbyte0 = (l >> 4) * 16;
#pragma unroll
  for (int kk = 0; kk < 4; ++kk) {
    int kb = kk * 64 + kbyte0;
    short8_t aF[2], bF[2];
#pragma unroll
    for (int mi = 0; mi < 2; ++mi) {
      int r = arow0 + mi * 16;
      aF[mi] = *(const short8_t*)(As + r * 256 + (kb ^ ((r & 7) << 4)));
    }
#pragma unroll
    for (int ni = 0; ni < 2; ++ni) {
      int r = brow0 + ni * 16;
      bF[ni] = *(const short8_t*)(Bs + r * 256 + (kb ^ ((r & 7) << 4)));
    }
#pragma unroll
    for (int mi = 0; mi < 2; ++mi)
#pragma unroll
      for (int ni = 0; ni < 2; ++ni)
        acc[mi][ni] = MFMA16(aF[mi], bF[ni], acc[mi][ni]);
  }

  int rbase = (l >> 4) * 4;
  int cl = l & 15;
  float invl2[2];
#pragma unroll
  for (int ni = 0; ni < 2; ++ni) invl2[ni] = invl[ni * 16 + cl];
#pragma unroll
  for (int mi = 0; mi < 2; ++mi) {
#pragma unroll
    for (int ni = 0; ni < 2; ++ni) {
      int n = n0 + ni * 16 + cl;
#pragma unroll
      for (int r = 0; r < 4; ++r) {
        int d = w * 32 + mi * 16 + rbase + r;
        float val = acc[mi][ni][r] * invl2[ni] + bias[d];
        size_t idx = ((size_t)b * NC + d) * NN + n;
        out[idx] = xres[idx] + val;
      }
    }
  }
}

// ---------------- K3: flash attention — K-tile swizzle deepened to 16 slots ---------
// K row stride is 256B = 16 slots; old 3-bit XOR left 8 lanes/slot-column (~4-way
// conflict, 4.19M counts). slot ^= (row&15) spreads over all 16 slots (~2-way, free).
// Involution preserved: same XOR on DMA source and LDS read (rule #21).
__device__ __forceinline__ void issue_kv32(const char* __restrict__ gKt,
                                           const char* __restrict__ gVt,
                                           char* Kbuf, char* Vbuf, int wg, int lane) {
#pragma unroll
  for (int i = 0; i < 2; ++i) {
    int ci = wg * 2 + i;
    int row = ci * 4 + (lane >> 4);                 // kv pos 0..31
    int col = (lane & 15) << 4;                     // 0..255
    gload_lds16(gKt + row * 256 + (col ^ ((row & 15) << 4)), Kbuf + ci * 1024);
  }
#pragma unroll
  for (int i = 0; i < 2; ++i) {
    int ci = wg * 2 + i;
    int rowl = lane >> 3;                           // row within chunk 0..7
    int sl = (lane & 7) ^ rowl;                     // logical slot (involution)
    int c = (ci * 8 + rowl) * 2 + (sl >> 2);        // channel 0..127
    int k16 = sl & 3;                               // 16B chunk within 64B kv window
    gload_lds16(gVt + (size_t)c * (NN * 2) + k16 * 16, Vbuf + ci * 1024);
  }
}

__global__ __launch_bounds__(256, 3) void attn(const unsigned short* __restrict__ q_t,
                                               const unsigned short* __restrict__ k_t,
                                               const unsigned short* __restrict__ v,
                                               unsigned short* __restrict__ O_p,
                                               float* __restrict__ l_p) {
  __shared__ __align__(16) char lds[32768];  // K0,K1 at 0,8K | V0,V1 at 16K,24K
  int qt = blockIdx.x, s = blockIdx.y, b = blockIdx.z;
  int tid = threadIdx.x, l = tid & 63, wg = tid >> 6;
  int ql = l & 31, qh = l >> 5;

  int t0 = 21 * s + min(s, 2);
  int cnt = 21 + (s < 2 ? 1 : 0);

  const char* gK = (const char*)(k_t + (size_t)b * NN * NC);
  const char* gV = (const char*)(v + (size_t)b * NC * NN);

  const unsigned short* gQ = q_t + ((size_t)b * NN + qt * 128 + wg * 32) * NC;
  short8_t bQ[8];
#pragma unroll
  for (int kk = 0; kk < 8; ++kk)
    bQ[kk] = *(const short8_t*)(gQ + (size_t)ql * NC + kk * 16 + qh * 8);

  issue_kv32(gK + (size_t)t0 * 8192, gV + (size_t)t0 * 64, lds, lds + 16384, wg, l);
  __syncthreads();

  f32x16_t oacc[4] = {};
  float lsum0 = 0.f, lsum1 = 0.f;

  for (int ti = 0; ti < cnt; ++ti) {
    int co = (ti & 1) << 13;
    int no = co ^ 8192;
    if (ti + 1 < cnt)
      issue_kv32(gK + (size_t)(t0 + ti + 1) * 8192, gV + (size_t)(t0 + ti + 1) * 64,
                 lds + no, lds + 16384 + no, wg, l);
    const char* Ks = lds + co;
    const char* Vs = lds + 16384 + co;

    f32x16_t sacc = {};
    __builtin_amdgcn_s_setprio(1);
#pragma unroll
    for (int kk = 0; kk < 8; ++kk) {
      short8_t aK = *(const short8_t*)(Ks + ql * 256 + ((kk * 32 + qh * 16) ^ ((ql & 15) << 4)));
      sacc = MFMA32(aK, bQ[kk], sacc);
    }
    __builtin_amdgcn_s_setprio(0);

    float p[16];
#pragma unroll
    for (int r = 0; r < 16; ++r) {
      p[r] = ex2(sacc[r] - FIXED_MAX2);
      if (r & 8) lsum1 += p[r]; else lsum0 += p[r];
    }

    unsigned int A0 = cvt_pk_bf16(p[0], p[1]), A1 = cvt_pk_bf16(p[2], p[3]);
    unsigned int B0 = cvt_pk_bf16(p[4], p[5]), B1 = cvt_pk_bf16(p[6], p[7]);
    unsigned int C0 = cvt_pk_bf16(p[8], p[9]), C1 = cvt_pk_bf16(p[10], p[11]);
    unsigned int D0 = cvt_pk_bf16(p[12], p[13]), D1 = cvt_pk_bf16(p[14], p[15]);
    uint2v_t r0 = __builtin_amdgcn_permlane32_swap(A0, B0, false, false);
    uint2v_t r1 = __builtin_amdgcn_permlane32_swap(A1, B1, false, false);
    uint2v_t r2 = __builtin_amdgcn_permlane32_swap(C0, D0, false, false);
    uint2v_t r3 = __builtin_amdgcn_permlane32_swap(C1, D1, false, false);
    uint4v_t pa0 = {r0.x, r1.x, r0.y, r1.y};   // kv (qh*8 + 0..7)
    uint4v_t pa1 = {r2.x, r3.x, r2.y, r3.y};   // kv (16 + qh*8 + 0..7)
    short8_t PA0 = __builtin_bit_cast(short8_t, pa0);
    short8_t PA1 = __builtin_bit_cast(short8_t, pa1);

    __builtin_amdgcn_s_setprio(1);
#pragma unroll
    for (int cb = 0; cb < 4; ++cb) {
#pragma unroll
      for (int ks = 0; ks < 2; ++ks) {
        int c = cb * 32 + ql;
        int row = c >> 1;
        int sl = ((c & 1) << 2) | (ks << 1) | qh;
        int pp = sl ^ (row & 7);
        short8_t aV = *(const short8_t*)(Vs + row * 128 + pp * 16);
        oacc[cb] = MFMA32(ks ? PA1 : PA0, aV, oacc[cb]);
      }
    }
    __builtin_amdgcn_s_setprio(0);

    __syncthreads();
  }

  float lanesum = lsum0 + lsum1;
  lanesum += __shfl_xor(lanesum, 32);

  unsigned short* Ob = O_p + ((size_t)(b * NS + s) * NN + qt * 128 + wg * 32) * 128;
#pragma unroll
  for (int r = 0; r < 16; ++r) {
    int q = (r & 3) + 8 * (r >> 2) + 4 * qh;
#pragma unroll
    for (int cb = 0; cb < 4; ++cb)
      Ob[(size_t)q * 128 + cb * 32 + ql] = f2bf(oacc[cb][r]);
  }
  if (l < 32)
    l_p[(size_t)(b * NS + s) * NN + qt * 128 + wg * 32 + ql] = lanesum;
}

// ---------------- launch ----------------
extern "C" void kernel_launch(void* const* d_in, const int* in_sizes, int n_in,
                              void* d_out, int out_size, void* d_ws, size_t ws_size,
                              hipStream_t stream) {
  const float* x = (const float*)d_in[0];
  const float* norm_w = (const float*)d_in[1];
  const float* norm_b = (const float*)d_in[2];
  const float* qkv_w = (const float*)d_in[3];
  const float* qkv_b = (const float*)d_in[4];
  const float* proj_w = (const float*)d_in[5];
  const float* proj_b = (const float*)d_in[6];
  float* out = (float*)d_out;

  char* ws = (char*)d_ws;
  float* mean = (float*)ws;
  float* rstd = (float*)(ws + 512);
  unsigned short* wq = (unsigned short*)(ws + 4096);
  unsigned short* wp = (unsigned short*)(ws + 4096 + 98304);
  const size_t TEN = (size_t)NB * NN * NC;          // 2M elems, 4MB bf16
  unsigned short* q_t = (unsigned short*)(ws + (1 << 18));
  unsigned short* k_t = q_t + TEN;
  unsigned short* v = k_t + TEN;
  unsigned short* O_p = (unsigned short*)(ws + (1 << 18) + 3 * TEN * 2);  // NS*4MB bf16
  float* l_p = (float*)((char*)O_p + (size_t)NS * NB * NN * NC * 2);      // NS*4*4096 f32

  gn_stats_convw<<<320, 256, 0, stream>>>(x, qkv_w, proj_w, mean, rstd, wq, wp);
  qkv_gemm<<<dim3(NN / 64, NB), 256, 0, stream>>>(x, mean, rstd, norm_w, norm_b,
                                                  wq, qkv_b, q_t, k_t, v);
  attn<<<dim3(NN / 128, NS, NB), 256, 0, stream>>>(q_t, k_t, v, O_p, l_p);
  proj_gemm<<<dim3(NN / 32, 1, NB), 256, 0, stream>>>(wp, O_p, l_p, proj_b, x, out);
}